// Round 2
// baseline (183.240 us; speedup 1.0000x reference)
//
#include <hip/hip_runtime.h>

// DYSPN fused kernel, 4-rows-per-block tile + LDS attention halo.
// out[b,h,w] = (G + att3)*cur/(S'+eps) + (1 - S_ppt/(S'+eps))*coarse
// where for k = i*7+j (k != 24; CENTER_MASK kills the center tap):
//   S_ppt = sum_k att[IDX[k]](h,w) * aff[k](h,w)            + att3(h,w)
//   S'    = sum_k att[IDX[k]](h,w) * |aff[k](h,w)|          + att3(h,w)
//   G     = sum_k att[IDX[k]](y,x) * aff[k](y,x),  (y,x)=(h+3-i, w+3-j), in-bounds
// Identity: fold7(kernel * unfold7(x))[h,w] == x[h,w] * sum_k kernel[k](h+3-i, w+3-j).

constexpr int H = 256, W = 256, HW = H * W;
constexpr int RB = 4;   // rows per block

__global__ __launch_bounds__(256, 4) void dyspn_kernel(
    const float* __restrict__ aff,    // [B,49,H,W]
    const float* __restrict__ attn,   // [B,4,H,W]
    const float* __restrict__ cur,    // [B,1,H,W]
    const float* __restrict__ coarse, // [B,1,H,W]
    float* __restrict__ out)          // [B,1,H,W]
{
    static constexpr int IDX[49] = {
        0,0,0,0,0,0,0,
        0,1,1,1,1,1,0,
        0,1,2,2,2,1,0,
        0,1,2,3,2,1,0,
        0,1,2,2,2,1,0,
        0,1,1,1,1,1,0,
        0,0,0,0,0,0,0};

    // Attention planes 0..2, rows h0-3 .. h0+6 (10 rows), staged in LDS.
    __shared__ float satt[3][RB + 6][W];   // 30 KB

    // XCD-aware bijective swizzle: 1024 blocks, 8 XCDs -> 128 contiguous
    // logical tiles per XCD so the +-3 row halo stays inside one XCD's L2.
    int bid = blockIdx.x;
    int logical = ((bid & 7) << 7) | (bid >> 3);
    int b  = logical >> 6;            // batch
    int h0 = (logical & 63) * RB;     // first row of tile
    int w  = threadIdx.x;             // col

    const float* __restrict__ affb = aff  + (size_t)b * 49 * HW;
    const float* __restrict__ attb = attn + (size_t)b * 4  * HW;

    // ---- stage attention halo (coalesced, zero-fill OOB rows) ----
#pragma unroll
    for (int idx = 0; idx < 3; ++idx) {
#pragma unroll
        for (int s = 0; s < RB + 6; ++s) {
            int y = h0 - 3 + s;
            float v = 0.f;
            if ((unsigned)y < (unsigned)H) v = attb[idx * HW + y * W + w];
            satt[idx][s][w] = v;
        }
    }
    __syncthreads();

    // Own-pixel attention values (from LDS) + self plane (global).
    float at_own[3][RB];
#pragma unroll
    for (int idx = 0; idx < 3; ++idx)
#pragma unroll
        for (int r = 0; r < RB; ++r)
            at_own[idx][r] = satt[idx][3 + r][w];

    float att_self[RB];
#pragma unroll
    for (int r = 0; r < RB; ++r)
        att_self[r] = attb[3 * HW + (h0 + r) * W + w];

    float sp[RB], sa[RB], G[RB];
#pragma unroll
    for (int r = 0; r < RB; ++r) { sp[r] = 0.f; sa[r] = 0.f; G[r] = 0.f; }

#pragma unroll
    for (int k = 0; k < 49; ++k) {
        if (k == 24) continue;                  // center tap masked
        const int i = k / 7;                    // compile-time after unroll
        const int j = k % 7;
        const int idx = IDX[k];
        const float* __restrict__ pk = affb + k * HW;
        const int x = w + 3 - j;                // shifted col (per-lane)
#pragma unroll
        for (int r = 0; r < RB; ++r) {
            // Own-pixel contribution to S_ppt / S'
            float a = pk[(h0 + r) * W + w];
            sp[r] = fmaf(at_own[idx][r], a, sp[r]);
            sa[r] = fmaf(at_own[idx][r], fabsf(a), sa[r]);
            // Shifted contribution to G (zero-pad = bounds check).
            int y = h0 + r + 3 - i;             // wave-uniform
            if ((unsigned)y < (unsigned)H && (unsigned)x < (unsigned)W) {
                float g = pk[y * W + x];
                G[r] = fmaf(satt[idx][r + 6 - i][x], g, G[r]);
            }
        }
    }

    // ---- epilogue ----
    const float* __restrict__ curb = cur    + (size_t)b * HW;
    const float* __restrict__ corb = coarse + (size_t)b * HW;
    float* __restrict__ outb       = out    + (size_t)b * HW;
#pragma unroll
    for (int r = 0; r < RB; ++r) {
        int p = (h0 + r) * W + w;
        float s_pr  = sa[r] + att_self[r];
        float s_ppt = sp[r] + att_self[r];
        float inv = 1.0f / (s_pr + 1e-6f);
        outb[p] = (G[r] + att_self[r]) * curb[p] * inv
                + (1.f - s_ppt * inv) * corb[p];
    }
}

extern "C" void kernel_launch(void* const* d_in, const int* in_sizes, int n_in,
                              void* d_out, int out_size, void* d_ws, size_t ws_size,
                              hipStream_t stream) {
    const float* aff    = (const float*)d_in[0];
    const float* attn   = (const float*)d_in[1];
    const float* cur    = (const float*)d_in[2];
    const float* coarse = (const float*)d_in[3];
    float* out = (float*)d_out;

    dim3 grid(16 * (256 / RB));   // B * H/RB = 1024 tiles
    dim3 block(256);              // one thread per column
    hipLaunchKernelGGL(dyspn_kernel, grid, block, 0, stream,
                       aff, attn, cur, coarse, out);
}

// Round 3
// 58.706 us; speedup vs baseline: 3.1213x; 3.1213x over previous
//
#include <hip/hip_runtime.h>

// DYSPN fused kernel, float4 vectorized (4 cols/thread), 2 rows/block.
// out[b,h,w] = (G + att3)*cur/(S'+eps) + (1 - S_ppt/(S'+eps))*coarse
// where for k = i*7+j (k != 24; CENTER_MASK kills the center tap):
//   S_ppt = sum_k att[IDX[k]](h,w) * aff[k](h,w)            + att3(h,w)
//   S'    = sum_k att[IDX[k]](h,w) * |aff[k](h,w)|          + att3(h,w)
//   G     = sum_k att[IDX[k]](y,x) * aff[k](y,x),  (y,x)=(h+3-i, w+3-j), in-bounds
// Identity: fold7(kernel * unfold7(x))[h,w] == x[h,w] * sum_k kernel[k](h+3-i, w+3-j).

typedef float f32x4 __attribute__((ext_vector_type(4)));

constexpr int H = 256, W = 256, HW = H * W;
constexpr int P4 = HW / 4;   // plane stride in float4
constexpr int RW = W / 4;    // row stride in float4 (64)

__global__ __launch_bounds__(128) void dyspn_kernel(
    const float* __restrict__ aff,    // [B,49,H,W]
    const float* __restrict__ attn,   // [B,4,H,W]
    const float* __restrict__ cur,    // [B,1,H,W]
    const float* __restrict__ coarse, // [B,1,H,W]
    float* __restrict__ out)          // [B,1,H,W]
{
    static constexpr int IDXR[7][7] = {
        {0,0,0,0,0,0,0},
        {0,1,1,1,1,1,0},
        {0,1,2,2,2,1,0},
        {0,1,2,3,2,1,0},
        {0,1,2,2,2,1,0},
        {0,1,1,1,1,1,0},
        {0,0,0,0,0,0,0}};
    // i processed in this order so i=3 (y==h) fills at_own first.
    static constexpr int IORD[7] = {3,0,1,2,4,5,6};

    // XCD-aware bijective swizzle: 2048 blocks, 8 XCDs -> 256 contiguous
    // logical tiles per XCD so the +-3 row halo stays in one XCD's L2.
    int bid = blockIdx.x;
    int logical = ((bid & 7) << 8) | (bid >> 3);
    int b  = logical >> 7;          // batch
    int rp = logical & 127;         // row-pair
    int tid = threadIdx.x;
    int r = tid >> 6;               // 0..1 (one wave per row)
    int w = tid & 63;               // col-group (4 cols each)
    int h = rp * 2 + r;

    const f32x4* __restrict__ aff4 = (const f32x4*)aff  + (size_t)b * 49 * P4;
    const f32x4* __restrict__ att4 = (const f32x4*)attn + (size_t)b * 4  * P4;
    const int hrow = h * RW;
    const int wm1 = (w == 0) ? 0 : w - 1;
    const int wp1 = (w == 63) ? 63 : w + 1;

    // Column-halo masks: segment concat element e maps to col 4w-4+e.
    // mlo[c] : e=c    (cols 4w-4+c), mhi[c] : e=8+c (cols 4w+4+c)
    bool mlo[4], mhi[4];
#pragma unroll
    for (int c = 0; c < 4; ++c) {
        mlo[c] = (unsigned)(4 * w - 4 + c) < 256u;
        mhi[c] = (unsigned)(4 * w + 4 + c) < 256u;
    }

    f32x4 sp = {0.f,0.f,0.f,0.f}, sa = {0.f,0.f,0.f,0.f}, G = {0.f,0.f,0.f,0.f};
    f32x4 at_own[3];                // att planes 0..2 at own pixels
    f32x4 seg[3][3];                // per-i attention row segments [idx][part]

#pragma unroll
    for (int ii = 0; ii < 7; ++ii) {
        const int i = IORD[ii];
        const int y = h + 3 - i;
        const bool yok = (unsigned)y < 256u;   // wave-uniform (wave = one row)
        const int ybase = y * RW;
        const int nidx = (i == 0 || i == 6) ? 1 : ((i == 1 || i == 5) ? 2 : 3);

        if (yok) {
            // Stage shifted-attention segments (cols [4w-4, 4w+7]) for the
            // idx planes this tap-row needs; zero the out-of-image halo.
#pragma unroll
            for (int idx = 0; idx < 3; ++idx) {
                if (idx >= nidx) continue;
                seg[idx][0] = att4[idx * P4 + ybase + wm1];
                seg[idx][1] = att4[idx * P4 + ybase + w];
                seg[idx][2] = att4[idx * P4 + ybase + wp1];
#pragma unroll
                for (int c = 0; c < 4; ++c) {
                    seg[idx][0][c] = mlo[c] ? seg[idx][0][c] : 0.f;
                    seg[idx][2][c] = mhi[c] ? seg[idx][2][c] : 0.f;
                }
            }
            if (i == 3) {           // y == h: own attention = middle part
                at_own[0] = seg[0][1];
                at_own[1] = seg[1][1];
                at_own[2] = seg[2][1];
            }
        }

#pragma unroll
        for (int j = 0; j < 7; ++j) {
            if (i == 3 && j == 3) continue;    // center tap masked
            const int k = i * 7 + j;
            const int idx = IDXR[i][j];
            const int d = 3 - j;               // column shift delta
            const f32x4* __restrict__ pk = aff4 + k * P4;

            // Own-pixel contribution to S_ppt / S'
            f32x4 a = pk[hrow + w];
#pragma unroll
            for (int c = 0; c < 4; ++c) {
                sp[c] = fmaf(at_own[idx][c], a[c], sp[c]);
                sa[c] = fmaf(at_own[idx][c], fabsf(a[c]), sa[c]);
            }

            // Shifted contribution to G (att segment already zero-padded,
            // so the spliced aff garbage at image edges is masked by *0).
            if (yok) {
                const int qa = (d < 0) ? wm1 : w;
                f32x4 A = pk[ybase + qa];
                f32x4 Bv = A;
                if (d != 0) {
                    const int qb = (d < 0) ? w : wp1;
                    Bv = pk[ybase + qb];
                }
                const int off = (d < 0) ? d + 4 : d;
#pragma unroll
                for (int c = 0; c < 4; ++c) {
                    const int e = d + 4 + c;               // 1..10
                    float tv = seg[idx][e >> 2][e & 3];    // shifted attention
                    float av = (off + c < 4) ? A[off + c] : Bv[off + c - 4];
                    G[c] = fmaf(tv, av, G[c]);
                }
            }
        }
    }

    // ---- epilogue ----
    f32x4 a3 = att4[3 * P4 + hrow + w];
    const f32x4* __restrict__ cur4 = (const f32x4*)cur    + (size_t)b * P4;
    const f32x4* __restrict__ cor4 = (const f32x4*)coarse + (size_t)b * P4;
    f32x4* __restrict__ out4       = (f32x4*)out          + (size_t)b * P4;
    f32x4 cu = cur4[hrow + w];
    f32x4 co = cor4[hrow + w];
    f32x4 o;
#pragma unroll
    for (int c = 0; c < 4; ++c) {
        float s_pr  = sa[c] + a3[c];
        float s_ppt = sp[c] + a3[c];
        float inv = 1.0f / (s_pr + 1e-6f);
        o[c] = (G[c] + a3[c]) * cu[c] * inv + (1.f - s_ppt * inv) * co[c];
    }
    out4[hrow + w] = o;
}

extern "C" void kernel_launch(void* const* d_in, const int* in_sizes, int n_in,
                              void* d_out, int out_size, void* d_ws, size_t ws_size,
                              hipStream_t stream) {
    const float* aff    = (const float*)d_in[0];
    const float* attn   = (const float*)d_in[1];
    const float* cur    = (const float*)d_in[2];
    const float* coarse = (const float*)d_in[3];
    float* out = (float*)d_out;

    dim3 grid(16 * 128);   // B * (H/2) row-pair tiles = 2048
    dim3 block(128);       // 2 rows x 64 col-groups (4 cols each)
    hipLaunchKernelGGL(dyspn_kernel, grid, block, 0, stream,
                       aff, attn, cur, coarse, out);
}

// Round 4
// 51.037 us; speedup vs baseline: 3.5903x; 1.1503x over previous
//
#include <hip/hip_runtime.h>

// DYSPN fused kernel, float4 vectorized, 8 rows/block (one wave per row).
// out[b,h,w] = (G + att3)*cur/(S'+eps) + (1 - S_ppt/(S'+eps))*coarse
// where for k = i*7+j (k != 24; CENTER_MASK kills the center tap):
//   S_ppt = sum_k att[IDX[k]](h,w) * aff[k](h,w)            + att3(h,w)
//   S'    = sum_k att[IDX[k]](h,w) * |aff[k](h,w)|          + att3(h,w)
//   G     = sum_k att[IDX[k]](y,x) * aff[k](y,x),  (y,x)=(h+3-i, w+3-j), in-bounds
// Identity: fold7(kernel * unfold7(x))[h,w] == x[h,w] * sum_k kernel[k](h+3-i, w+3-j).
//
// R4 structural change vs R3: 8 rows per block so the per-plane halo window
// (8+6 rows = 14 KB) is L1-resident and halo over-fetch drops from 4x to 1.75x.

typedef float f32x4 __attribute__((ext_vector_type(4)));

constexpr int H = 256, W = 256, HW = H * W;
constexpr int P4 = HW / 4;   // plane stride in float4
constexpr int RW = W / 4;    // row stride in float4 (64)
constexpr int RB = 8;        // rows per block (8 waves, one row per wave)

__global__ __launch_bounds__(512) void dyspn_kernel(
    const float* __restrict__ aff,    // [B,49,H,W]
    const float* __restrict__ attn,   // [B,4,H,W]
    const float* __restrict__ cur,    // [B,1,H,W]
    const float* __restrict__ coarse, // [B,1,H,W]
    float* __restrict__ out)          // [B,1,H,W]
{
    static constexpr int IDXR[7][7] = {
        {0,0,0,0,0,0,0},
        {0,1,1,1,1,1,0},
        {0,1,2,2,2,1,0},
        {0,1,2,3,2,1,0},
        {0,1,2,2,2,1,0},
        {0,1,1,1,1,1,0},
        {0,0,0,0,0,0,0}};
    // i processed in this order so i=3 (y==h) fills at_own first.
    static constexpr int IORD[7] = {3,0,1,2,4,5,6};

    // XCD-aware bijective swizzle: 512 blocks, 8 XCDs -> 64 contiguous
    // logical tiles (= 2 whole images) per XCD, so vertically adjacent
    // tiles sharing the 3-row halo run on the same XCD's L2.
    int bid = blockIdx.x;
    int logical = ((bid & 7) << 6) | (bid >> 3);
    int b  = logical >> 5;            // batch (16)
    int t  = logical & 31;            // row-tile within image (32)
    int tid = threadIdx.x;
    int r = tid >> 6;                 // 0..7 (one wave per row)
    int w = tid & 63;                 // col-group (4 cols each)
    int h = t * RB + r;

    const f32x4* __restrict__ aff4 = (const f32x4*)aff  + (size_t)b * 49 * P4;
    const f32x4* __restrict__ att4 = (const f32x4*)attn + (size_t)b * 4  * P4;
    const int hrow = h * RW;
    const int wm1 = (w == 0) ? 0 : w - 1;
    const int wp1 = (w == 63) ? 63 : w + 1;

    // Column-halo masks: segment concat element e maps to col 4w-4+e.
    bool mlo[4], mhi[4];
#pragma unroll
    for (int c = 0; c < 4; ++c) {
        mlo[c] = (unsigned)(4 * w - 4 + c) < 256u;
        mhi[c] = (unsigned)(4 * w + 4 + c) < 256u;
    }

    f32x4 sp = {0.f,0.f,0.f,0.f}, sa = {0.f,0.f,0.f,0.f}, G = {0.f,0.f,0.f,0.f};
    f32x4 at_own[3];                // att planes 0..2 at own pixels
    f32x4 seg[3][3];                // per-i attention row segments [idx][part]

#pragma unroll
    for (int ii = 0; ii < 7; ++ii) {
        const int i = IORD[ii];
        const int y = h + 3 - i;
        const bool yok = (unsigned)y < 256u;   // wave-uniform (wave = one row)
        const int ybase = y * RW;
        const int nidx = (i == 0 || i == 6) ? 1 : ((i == 1 || i == 5) ? 2 : 3);

        if (yok) {
            // Stage shifted-attention segments (cols [4w-4, 4w+7]) for the
            // idx planes this tap-row needs; zero the out-of-image halo.
#pragma unroll
            for (int idx = 0; idx < 3; ++idx) {
                if (idx >= nidx) continue;
                seg[idx][0] = att4[idx * P4 + ybase + wm1];
                seg[idx][1] = att4[idx * P4 + ybase + w];
                seg[idx][2] = att4[idx * P4 + ybase + wp1];
#pragma unroll
                for (int c = 0; c < 4; ++c) {
                    seg[idx][0][c] = mlo[c] ? seg[idx][0][c] : 0.f;
                    seg[idx][2][c] = mhi[c] ? seg[idx][2][c] : 0.f;
                }
            }
            if (i == 3) {           // y == h: own attention = middle part
                at_own[0] = seg[0][1];
                at_own[1] = seg[1][1];
                at_own[2] = seg[2][1];
            }
        }

#pragma unroll
        for (int j = 0; j < 7; ++j) {
            if (i == 3 && j == 3) continue;    // center tap masked
            const int k = i * 7 + j;
            const int idx = IDXR[i][j];
            const int d = 3 - j;               // column shift delta
            const f32x4* __restrict__ pk = aff4 + k * P4;

            // Own-pixel contribution to S_ppt / S'
            f32x4 a = pk[hrow + w];
#pragma unroll
            for (int c = 0; c < 4; ++c) {
                sp[c] = fmaf(at_own[idx][c], a[c], sp[c]);
                sa[c] = fmaf(at_own[idx][c], fabsf(a[c]), sa[c]);
            }

            // Shifted contribution to G (att segment already zero-padded,
            // so the spliced aff garbage at image edges is masked by *0).
            if (yok) {
                const int qa = (d < 0) ? wm1 : w;
                f32x4 A = pk[ybase + qa];
                f32x4 Bv = A;
                if (d != 0) {
                    const int qb = (d < 0) ? w : wp1;
                    Bv = pk[ybase + qb];
                }
                const int off = (d < 0) ? d + 4 : d;
#pragma unroll
                for (int c = 0; c < 4; ++c) {
                    const int e = d + 4 + c;               // 1..10
                    float tv = seg[idx][e >> 2][e & 3];    // shifted attention
                    float av = (off + c < 4) ? A[off + c] : Bv[off + c - 4];
                    G[c] = fmaf(tv, av, G[c]);
                }
            }
        }
    }

    // ---- epilogue ----
    f32x4 a3 = att4[3 * P4 + hrow + w];
    const f32x4* __restrict__ cur4 = (const f32x4*)cur    + (size_t)b * P4;
    const f32x4* __restrict__ cor4 = (const f32x4*)coarse + (size_t)b * P4;
    f32x4* __restrict__ out4       = (f32x4*)out          + (size_t)b * P4;
    f32x4 cu = cur4[hrow + w];
    f32x4 co = cor4[hrow + w];
    f32x4 o;
#pragma unroll
    for (int c = 0; c < 4; ++c) {
        float s_pr  = sa[c] + a3[c];
        float s_ppt = sp[c] + a3[c];
        float inv = 1.0f / (s_pr + 1e-6f);
        o[c] = (G[c] + a3[c]) * cu[c] * inv + (1.f - s_ppt * inv) * co[c];
    }
    out4[hrow + w] = o;
}

extern "C" void kernel_launch(void* const* d_in, const int* in_sizes, int n_in,
                              void* d_out, int out_size, void* d_ws, size_t ws_size,
                              hipStream_t stream) {
    const float* aff    = (const float*)d_in[0];
    const float* attn   = (const float*)d_in[1];
    const float* cur    = (const float*)d_in[2];
    const float* coarse = (const float*)d_in[3];
    float* out = (float*)d_out;

    dim3 grid(16 * 32);    // B * (H/RB) = 512 tiles
    dim3 block(512);       // 8 rows x 64 col-groups (4 cols each)
    hipLaunchKernelGGL(dyspn_kernel, grid, block, 0, stream,
                       aff, attn, cur, coarse, out);
}